// Round 2
// baseline (410.765 us; speedup 1.0000x reference)
//
#include <hip/hip_runtime.h>
#include <stdint.h>

typedef _Float16 h8 __attribute__((ext_vector_type(8)));
typedef _Float16 h4 __attribute__((ext_vector_type(4)));
typedef float f32x4 __attribute__((ext_vector_type(4)));

// workspace byte offsets (total ~49 MB; opart/ml reuse dead Wc/FT regions)
#define WS_WC   0u          // _Float16 [384][1024] combined weights (dead after k_gemm)
#define WS_BIAS 786432u     // float [384] combined bias
#define WS_FT   1048576u    // _Float16 [4][4096][1024] feats^T (dead after k_gemm)
#define WS_QKVT 34603008u   // _Float16 [4][4096][384]  q|k|v, n-major
#define WS_VT   47185920u   // _Float16 [4][128][4096]  v, d-major
#define WS_OP   WS_FT       // float [4 part][4 b][128 d][4096 n] partial O (32 MB, over FT)
#define WS_MLM  0u          // float [4 part][4 b][4096] running max (over Wc)
#define WS_MLL  262144u     // float [4 part][4 b][4096] running sum (over Wc)

// ---------------- kernel 0: fold projections: Wc = [w1;w2;w3] @ PW ----------------
__global__ void k_weights(const float* __restrict__ pw, const float* __restrict__ pb,
                          const float* __restrict__ w1, const float* __restrict__ b1,
                          const float* __restrict__ w2, const float* __restrict__ b2,
                          const float* __restrict__ w3, const float* __restrict__ b3,
                          _Float16* __restrict__ Wc, float* __restrict__ bc)
{
  int idx = blockIdx.x * 256 + threadIdx.x;          // 384*1024 total
  int o3 = idx >> 10, ck = idx & 1023;
  const float* wg = (o3 < 128) ? w1 : (o3 < 256 ? w2 : w3);
  int o = o3 & 127;
  float s = 0.f;
  #pragma unroll 8
  for (int c = 0; c < 128; ++c) s += wg[o * 128 + c] * pw[c * 1024 + ck];
  Wc[idx] = (_Float16)s;
  if (idx < 384) {
    const float* wgb = (idx < 128) ? w1 : (idx < 256 ? w2 : w3);
    const float* bg  = (idx < 128) ? b1 : (idx < 256 ? b2 : b3);
    int oo = idx & 127;
    float sb = bg[oo];
    for (int c = 0; c < 128; ++c) sb += wgb[oo * 128 + c] * pb[c];
    bc[idx] = sb;
  }
}

// ---------------- kernel 1: feats (b,1024,4096) f32 -> feats^T (b,4096,1024) fp16 ----------------
__global__ void k_featT(const float* __restrict__ feats, _Float16* __restrict__ FT)
{
  __shared__ float tile[64][65];                     // +1 pad: conflict-free column reads
  const int ck0 = blockIdx.x * 64, n0 = blockIdx.y * 64, b = blockIdx.z;
  const int t = threadIdx.x;
  const float* src = feats + ((size_t)(b * 1024 + ck0)) * 4096 + n0;
  #pragma unroll
  for (int p = 0; p < 4; ++p) {
    int i = t + p * 256, row = i >> 4, slot = i & 15; // row=ck, 4 floats per slot
    float4 g = *(const float4*)(src + (size_t)row * 4096 + slot * 4);
    tile[row][slot * 4 + 0] = g.x; tile[row][slot * 4 + 1] = g.y;
    tile[row][slot * 4 + 2] = g.z; tile[row][slot * 4 + 3] = g.w;
  }
  __syncthreads();
  _Float16* dst = FT + ((size_t)(b * 4096 + n0)) * 1024 + ck0;
  #pragma unroll
  for (int p = 0; p < 4; ++p) {
    int i = t + p * 256, n = i >> 4, cs = i & 15;
    h4 o;
    #pragma unroll
    for (int j = 0; j < 4; ++j) o[j] = (_Float16)tile[cs * 4 + j][n];
    *(h4*)(dst + (size_t)n * 1024 + cs * 4) = o;
  }
}

// ---------------- kernel 2: qkvt[b][n][o] = FT[b][n][:] . Wc[o][:] + bias[o] ----------------
// M=4096(n) x N=384(o) x K=1024. BM=BN=128, BK=64, 4 waves (2x2), 16x16x32 fp16 MFMA.
__global__ __launch_bounds__(256) void k_gemm(const _Float16* __restrict__ FT,
                                              const _Float16* __restrict__ Wc,
                                              const float* __restrict__ bc,
                                              _Float16* __restrict__ qkvt)
{
  extern __shared__ char smem[];                     // 2 bufs x (A 16K + W 16K) = 64K
  const int t = threadIdx.x, lane = t & 63, w = t >> 6;
  const int lo = lane & 15, hi = lane >> 4;
  const int bx = blockIdx.x, by = blockIdx.y, bz = blockIdx.z;
  const int n0 = by * 128;
  const int wr = w >> 1, wc = w & 1;
  const int nb_ = wr * 64, ob_ = wc * 64;

  uint4 areg[4], wreg[4];
  const char* Fbase = (const char*)FT + ((size_t)(bz * 4096 + n0)) * 2048;
  const char* Wbase = (const char*)Wc + ((size_t)(bx * 128)) * 2048;

  auto stageload = [&](int s) {
    const char* Fb = Fbase + s * 128;
    const char* Wb = Wbase + s * 128;
    #pragma unroll
    for (int p = 0; p < 4; ++p) {
      int i = t + p * 256, row = i >> 3, slot = i & 7;
      areg[p] = *(const uint4*)(Fb + (size_t)row * 2048 + slot * 16);
      wreg[p] = *(const uint4*)(Wb + (size_t)row * 2048 + slot * 16);
    }
  };
  auto stagewrite = [&](int buf) {
    char* base = smem + buf * 32768;
    #pragma unroll
    for (int p = 0; p < 4; ++p) {
      int i = t + p * 256, row = i >> 3, slot = i & 7;
      int off = row * 128 + ((slot * 16) ^ ((row & 7) << 4));
      *(uint4*)(base + off) = areg[p];
      *(uint4*)(base + 16384 + off) = wreg[p];
    }
  };

  const f32x4 zero4 = {0.f, 0.f, 0.f, 0.f};
  f32x4 acc[4][4];
  #pragma unroll
  for (int i2 = 0; i2 < 4; ++i2)
    #pragma unroll
    for (int j2 = 0; j2 < 4; ++j2) acc[i2][j2] = zero4;

  stageload(0); stagewrite(0);
  for (int s = 0; s < 16; ++s) {
    __syncthreads();
    if (s < 15) stageload(s + 1);
    const char* base = smem + (s & 1) * 32768;
    #pragma unroll
    for (int kk = 0; kk < 2; ++kk) {
      const int cb = kk * 64 + hi * 16;
      h8 af[4], bf[4];
      #pragma unroll
      for (int i2 = 0; i2 < 4; ++i2) {
        int row = nb_ + i2 * 16 + lo;
        af[i2] = *(const h8*)(base + row * 128 + (cb ^ ((row & 7) << 4)));
      }
      #pragma unroll
      for (int j2 = 0; j2 < 4; ++j2) {
        int row = ob_ + j2 * 16 + lo;
        bf[j2] = *(const h8*)(base + 16384 + row * 128 + (cb ^ ((row & 7) << 4)));
      }
      #pragma unroll
      for (int i2 = 0; i2 < 4; ++i2)
        #pragma unroll
        for (int j2 = 0; j2 < 4; ++j2)
          acc[i2][j2] = __builtin_amdgcn_mfma_f32_16x16x32_f16(af[i2], bf[j2], acc[i2][j2], 0, 0, 0);
    }
    if (s < 15) stagewrite((s + 1) & 1);
  }

  float bias[4];
  #pragma unroll
  for (int j2 = 0; j2 < 4; ++j2) bias[j2] = bc[bx * 128 + ob_ + j2 * 16 + lo];
  #pragma unroll
  for (int i2 = 0; i2 < 4; ++i2)
    #pragma unroll
    for (int j2 = 0; j2 < 4; ++j2)
      #pragma unroll
      for (int r = 0; r < 4; ++r) {
        int nrel = n0 + nb_ + i2 * 16 + hi * 4 + r;
        int ocol = bx * 128 + ob_ + j2 * 16 + lo;
        qkvt[((size_t)(bz * 4096 + nrel)) * 384 + ocol] = (_Float16)(acc[i2][j2][r] + bias[j2]);
      }
}

// ---------------- kernel 3: v slice of qkvt (n-major) -> v_t[b][d][m] (d-major) ----------------
__global__ void k_vtrans(const _Float16* __restrict__ qkvt, _Float16* __restrict__ vt)
{
  __shared__ char tl[64 * 256];                      // [m 64][d 128] fp16, swizzled
  const int mt = blockIdx.x, b = blockIdx.y, t = threadIdx.x;
  const int m0 = mt * 64;
  #pragma unroll
  for (int p = 0; p < 4; ++p) {
    int i = t + p * 256, m = i >> 4, slot = i & 15;
    uint4 g = *(const uint4*)((const char*)qkvt + ((size_t)(b * 4096 + m0 + m)) * 768 + 512 + slot * 16);
    *(uint4*)(tl + m * 256 + ((slot * 16) ^ ((m & 7) << 4))) = g;
  }
  __syncthreads();
  #pragma unroll
  for (int p = 0; p < 8; ++p) {
    int i = t + p * 256, d = i >> 4, ms = i & 15;
    h4 o;
    #pragma unroll
    for (int j = 0; j < 4; ++j) {
      int m = ms * 4 + j;
      o[j] = *(const _Float16*)(tl + m * 256 + ((2 * d) ^ ((m & 7) << 4)));
    }
    *(h4*)((char*)vt + ((size_t)(b * 128 + d)) * 8192 + (m0 + ms * 4) * 2) = o;
  }
}

// ---------------- kernel 4: split-KV flash attention partials ----------------
// grid 1024 = 4 parts x 4 b x 64 qtiles; 64 queries/block, 4 waves x 16 q-rows.
// NO K/V LDS staging (L2-resident via XCD pinning), NO barriers in main loop.
// Writes unnormalized O^T partial [p][b][d][n] f32 + per-row (m, l).
#define ATT_LDS 8192
__global__ __launch_bounds__(256) void k_attn_part(const _Float16* __restrict__ qkvt,
                                                   const _Float16* __restrict__ vt,
                                                   float* __restrict__ opart,
                                                   float* __restrict__ mlm,
                                                   float* __restrict__ mll)
{
  extern __shared__ char smem[];                     // per-wave P [16][64] fp16 swizzled
  const int t = threadIdx.x, lane = t & 63, w = t >> 6;
  const int lo = lane & 15, hi = lane >> 4;
  // XCD swizzle: XCD x (= id%8) gets vid in [x*128,(x+1)*128) => bp in {2x,2x+1},
  // so each XCD's hot set = Q/K slices of one batch pair of parts + V chunks (~2 MB, L2-fits)
  const int id = blockIdx.x;
  const int vid = (id & 7) * 128 + (id >> 3);
  const int qt = vid & 63, bp = vid >> 6;
  const int b = bp >> 2, p = bp & 3;
  const int n0 = qt * 64;
  const char* qbase = (const char*)qkvt + (size_t)b * 4096 * 768;
  const char* vbase = (const char*)vt + (size_t)b * 128 * 8192;

  // Q fragments straight from global (one-time, L2)
  h8 aq[4];
  {
    const char* qr = qbase + (size_t)(n0 + w * 16 + lo) * 768;
    #pragma unroll
    for (int dk = 0; dk < 4; ++dk) aq[dk] = *(const h8*)(qr + dk * 64 + hi * 16);
  }

  const f32x4 zero4 = {0.f, 0.f, 0.f, 0.f};
  float m_run[4], l_run[4];
  #pragma unroll
  for (int r = 0; r < 4; ++r) { m_run[r] = -1e30f; l_run[r] = 0.f; }
  f32x4 oacc[8];
  #pragma unroll
  for (int dt = 0; dt < 8; ++dt) oacc[dt] = zero4;

  char* pmine = smem + w * 2048;
  const int rq = lo & 3;
  const int bsrc = (lo >> 2) << 4;                   // broadcast source lane for col-layout
  const char* vrow = vbase + (size_t)lo * 8192;      // + dt*16*8192 + m-offset

  for (int it = 0; it < 16; ++it) {
    const int m0 = p * 1024 + it * 64;

    // ---- S = Q K^T, K fragments direct from global ----
    f32x4 s[4];
    #pragma unroll
    for (int mt = 0; mt < 4; ++mt) s[mt] = zero4;
    __builtin_amdgcn_s_setprio(1);
    #pragma unroll
    for (int mt = 0; mt < 4; ++mt) {
      const char* kr = qbase + (size_t)(m0 + mt * 16 + lo) * 768 + 256;
      #pragma unroll
      for (int dk = 0; dk < 4; ++dk) {
        h8 bk = *(const h8*)(kr + dk * 64 + hi * 16);
        s[mt] = __builtin_amdgcn_mfma_f32_16x16x32_f16(aq[dk], bk, s[mt], 0, 0, 0);
      }
    }
    __builtin_amdgcn_s_setprio(0);

    // ---- online softmax (rows = queries; 16 lanes hold one row's 16 keys per mt) ----
    float sc[4];
    #pragma unroll
    for (int r = 0; r < 4; ++r) {
      float mx = fmaxf(fmaxf(s[0][r], s[1][r]), fmaxf(s[2][r], s[3][r]));
      mx = fmaxf(mx, __shfl_xor(mx, 1)); mx = fmaxf(mx, __shfl_xor(mx, 2));
      mx = fmaxf(mx, __shfl_xor(mx, 4)); mx = fmaxf(mx, __shfl_xor(mx, 8));
      float mnew = fmaxf(m_run[r], mx);
      sc[r] = __expf(m_run[r] - mnew);
      float p0 = __expf(s[0][r] - mnew), p1 = __expf(s[1][r] - mnew);
      float p2 = __expf(s[2][r] - mnew), p3 = __expf(s[3][r] - mnew);
      float rs = p0 + p1 + p2 + p3;
      rs += __shfl_xor(rs, 1); rs += __shfl_xor(rs, 2);
      rs += __shfl_xor(rs, 4); rs += __shfl_xor(rs, 8);
      l_run[r] = l_run[r] * sc[r] + rs;
      m_run[r] = mnew;
      const int prow = hi * 4 + r, psw = (prow & 7) << 4;
      *(_Float16*)(pmine + prow * 128 + ((2 * (0  + lo)) ^ psw)) = (_Float16)p0;
      *(_Float16*)(pmine + prow * 128 + ((2 * (16 + lo)) ^ psw)) = (_Float16)p1;
      *(_Float16*)(pmine + prow * 128 + ((2 * (32 + lo)) ^ psw)) = (_Float16)p2;
      *(_Float16*)(pmine + prow * 128 + ((2 * (48 + lo)) ^ psw)) = (_Float16)p3;
    }

    // rescale O^T (cols = queries): broadcast per-row scale to col layout
    {
      float c0 = __shfl(sc[0], bsrc), c1 = __shfl(sc[1], bsrc);
      float c2 = __shfl(sc[2], bsrc), c3 = __shfl(sc[3], bsrc);
      float scol = (rq == 0) ? c0 : (rq == 1) ? c1 : (rq == 2) ? c2 : c3;
      #pragma unroll
      for (int dt = 0; dt < 8; ++dt) oacc[dt] *= scol;
    }

    // ---- O^T += V^T P^T, V fragments direct from global (L2) ----
    __builtin_amdgcn_s_setprio(1);
    #pragma unroll
    for (int kk = 0; kk < 2; ++kk) {
      const int prow2 = lo;
      h8 bpf = *(const h8*)(pmine + prow2 * 128 + ((kk * 64 + hi * 16) ^ ((prow2 & 7) << 4)));
      #pragma unroll
      for (int dt = 0; dt < 8; ++dt) {
        h8 av = *(const h8*)(vrow + (size_t)dt * 131072 + m0 * 2 + kk * 64 + hi * 16);
        oacc[dt] = __builtin_amdgcn_mfma_f32_16x16x32_f16(av, bpf, oacc[dt], 0, 0, 0);
      }
    }
    __builtin_amdgcn_s_setprio(0);
  }

  // ---- store unnormalized partial O^T [p][b][d][n] + (m, l) per q-row ----
  float* op = opart + ((size_t)((p * 4 + b) * 128)) * 4096;
  const int ncol = n0 + w * 16 + lo;
  #pragma unroll
  for (int dt = 0; dt < 8; ++dt)
    #pragma unroll
    for (int r = 0; r < 4; ++r) {
      int d = dt * 16 + hi * 4 + r;
      op[(size_t)d * 4096 + ncol] = oacc[dt][r];
    }
  if (lo == 0) {
    size_t mlbase = (size_t)(p * 4 + b) * 4096 + n0 + w * 16 + hi * 4;
    #pragma unroll
    for (int r = 0; r < 4; ++r) {
      mlm[mlbase + r] = m_run[r];
      mll[mlbase + r] = l_run[r];
    }
  }
}

// ---------------- kernel 5: combine 4 KV-partials ----------------
__global__ void k_reduce(const float* __restrict__ opart, const float* __restrict__ mlm,
                         const float* __restrict__ mll, float* __restrict__ out)
{
  int idx = blockIdx.x * 256 + threadIdx.x;          // 4b*128d*1024(n/4) = 524288
  int n4 = idx & 1023, d = (idx >> 10) & 127, b = idx >> 17;
  int n0 = n4 * 4;
  f32x4 m[4], lv[4];
  #pragma unroll
  for (int p = 0; p < 4; ++p) {
    size_t mb = (size_t)(p * 4 + b) * 4096 + n0;
    m[p]  = *(const f32x4*)(mlm + mb);
    lv[p] = *(const f32x4*)(mll + mb);
  }
  f32x4 M = m[0];
  #pragma unroll
  for (int p = 1; p < 4; ++p)
    #pragma unroll
    for (int j = 0; j < 4; ++j) M[j] = fmaxf(M[j], m[p][j]);
  f32x4 denom = {0.f, 0.f, 0.f, 0.f}, num = {0.f, 0.f, 0.f, 0.f};
  #pragma unroll
  for (int p = 0; p < 4; ++p) {
    f32x4 o = *(const f32x4*)(opart + ((size_t)((p * 4 + b) * 128 + d)) * 4096 + n0);
    #pragma unroll
    for (int j = 0; j < 4; ++j) {
      float e = __expf(m[p][j] - M[j]);
      denom[j] += lv[p][j] * e;
      num[j]   += o[j] * e;
    }
  }
  f32x4 r;
  #pragma unroll
  for (int j = 0; j < 4; ++j) r[j] = num[j] / denom[j];
  *(f32x4*)(out + ((size_t)(b * 128 + d)) * 4096 + n0) = r;
}

extern "C" void kernel_launch(void* const* d_in, const int* in_sizes, int n_in,
                              void* d_out, int out_size, void* d_ws, size_t ws_size,
                              hipStream_t stream)
{
  const float* feats = (const float*)d_in[0];
  const float* pw = (const float*)d_in[1];
  const float* pb = (const float*)d_in[2];
  const float* w1 = (const float*)d_in[3];
  const float* b1 = (const float*)d_in[4];
  const float* w2 = (const float*)d_in[5];
  const float* b2 = (const float*)d_in[6];
  const float* w3 = (const float*)d_in[7];
  const float* b3 = (const float*)d_in[8];
  char* ws = (char*)d_ws;
  _Float16* Wc = (_Float16*)(ws + WS_WC);
  float* bc = (float*)(ws + WS_BIAS);
  _Float16* FT = (_Float16*)(ws + WS_FT);
  _Float16* qkvt = (_Float16*)(ws + WS_QKVT);
  _Float16* vt = (_Float16*)(ws + WS_VT);
  float* opart = (float*)(ws + WS_OP);
  float* mlm = (float*)(ws + WS_MLM);
  float* mll = (float*)(ws + WS_MLL);
  float* out = (float*)d_out;

  hipLaunchKernelGGL(k_weights, dim3(1536), dim3(256), 0, stream,
                     pw, pb, w1, b1, w2, b2, w3, b3, Wc, bc);
  hipLaunchKernelGGL(k_featT, dim3(16, 64, 4), dim3(256), 0, stream, feats, FT);
  hipLaunchKernelGGL(k_gemm, dim3(3, 32, 4), dim3(256), 65536, stream, FT, Wc, bc, qkvt);
  hipLaunchKernelGGL(k_vtrans, dim3(64, 4), dim3(256), 0, stream, qkvt, vt);
  hipLaunchKernelGGL(k_attn_part, dim3(1024), dim3(256), ATT_LDS, stream, qkvt, vt, opart, mlm, mll);
  hipLaunchKernelGGL(k_reduce, dim3(2048), dim3(256), 0, stream, opart, mlm, mll, out);
}

// Round 3
// 156.016 us; speedup vs baseline: 2.6328x; 2.6328x over previous
//
#include <hip/hip_runtime.h>
#include <stdint.h>

typedef _Float16 h8 __attribute__((ext_vector_type(8)));
typedef _Float16 h4 __attribute__((ext_vector_type(4)));
typedef _Float16 h2 __attribute__((ext_vector_type(2)));
typedef float f32x4 __attribute__((ext_vector_type(4)));
typedef uint32_t u32x4 __attribute__((ext_vector_type(4)));

// workspace map (<= 51380224 bytes, same footprint as R1/R2)
#define WS_PWH  0u          // _Float16 [128][1024]  (dead after gemm1; mlm overwrites)
#define WS_WH   262144u     // _Float16 [384][128]   (dead after gemm2; mll overwrites)
#define WS_BC   600064u     // float [384]
#define WS_FT   1048576u    // _Float16 [4][4096][1024] feats^T; F2D aliases first 256B of each row
#define WS_QKVT 34603008u   // _Float16 [4][4096][384] q|k|v, n-major
#define WS_VT   47185920u   // _Float16 [4][128][4096] v, d-major
#define WS_OP   WS_FT       // float [4p][4b][128][4096] partial O (32MB over FT)
#define WS_MLM  0u          // float [16][4096]
#define WS_MLL  262144u     // float [16][4096]

__device__ __forceinline__ void gll16(const void* g, void* l) {
  __builtin_amdgcn_global_load_lds((const __attribute__((address_space(1))) unsigned int*)g,
                                   (__attribute__((address_space(3))) unsigned int*)l, 16, 0, 0);
}

// ---------------- kernel 0: casts + combined bias bc = b + W*pb ----------------
__global__ void k_cvt(const float* __restrict__ pw, const float* __restrict__ pb,
                      const float* __restrict__ w1, const float* __restrict__ b1,
                      const float* __restrict__ w2, const float* __restrict__ b2,
                      const float* __restrict__ w3, const float* __restrict__ b3,
                      _Float16* __restrict__ PWh, _Float16* __restrict__ Wh,
                      float* __restrict__ bc)
{
  int idx = blockIdx.x * 256 + threadIdx.x;
  if (idx < 131072) {
    PWh[idx] = (_Float16)pw[idx];                    // pw already [o][c*8+l] row-major
  } else {
    int j = idx - 131072;
    if (j < 49152) {
      int g = j >> 14, rem = j & 16383;
      const float* wg = (g == 0) ? w1 : (g == 1 ? w2 : w3);
      Wh[j] = (_Float16)wg[rem];
    }
  }
  if (idx < 384) {
    int g = idx >> 7, o = idx & 127;
    const float* wg = (g == 0) ? w1 : (g == 1 ? w2 : w3);
    const float* bg = (g == 0) ? b1 : (g == 1 ? b2 : b3);
    float s = bg[o];
    for (int c = 0; c < 128; ++c) s += wg[o * 128 + c] * pb[c];
    bc[idx] = s;
  }
}

// ---------------- kernel 1: feats (b,1024,4096) f32 -> feats^T (b,4096,1024) fp16 ----------------
__global__ void k_featT(const float* __restrict__ feats, _Float16* __restrict__ FT)
{
  __shared__ float tile[64][65];
  const int ck0 = blockIdx.x * 64, n0 = blockIdx.y * 64, b = blockIdx.z;
  const int t = threadIdx.x;
  const float* src = feats + ((size_t)(b * 1024 + ck0)) * 4096 + n0;
  #pragma unroll
  for (int p = 0; p < 4; ++p) {
    int i = t + p * 256, row = i >> 4, slot = i & 15;
    float4 g = *(const float4*)(src + (size_t)row * 4096 + slot * 4);
    tile[row][slot * 4 + 0] = g.x; tile[row][slot * 4 + 1] = g.y;
    tile[row][slot * 4 + 2] = g.z; tile[row][slot * 4 + 3] = g.w;
  }
  __syncthreads();
  _Float16* dst = FT + ((size_t)(b * 4096 + n0)) * 1024 + ck0;
  #pragma unroll
  for (int p = 0; p < 4; ++p) {
    int i = t + p * 256, n = i >> 4, cs = i & 15;
    h4 o;
    #pragma unroll
    for (int j = 0; j < 4; ++j) o[j] = (_Float16)tile[cs * 4 + j][n];
    *(h4*)(dst + (size_t)n * 1024 + cs * 4) = o;
  }
}

// ---------------- kernel 2: GEMM1  F2D[b][n][128] = FT[b][n][:] . PWh[o][:]  (no bias) ----------------
// M=4096 x N=128 x K=1024, BM=64 BN=128 BK=64, 4 waves (2x2). F2D row aliased into FT row (first 256B).
__global__ __launch_bounds__(256) void k_gemm1(char* __restrict__ ftbase,
                                               const _Float16* __restrict__ PWh)
{
  extern __shared__ char smem[];                     // 2 bufs x (A 8K + B 16K) = 48K
  const int t = threadIdx.x, lane = t & 63, w = t >> 6;
  const int lo = lane & 15, hi = lane >> 4;
  const int n0 = blockIdx.x * 64, b = blockIdx.y;
  const int wr = w >> 1, wc = w & 1;
  const int nb = wr * 32, ob = wc * 64;

  uint4 areg[2], wreg[4];
  const char* Fbase = ftbase + ((size_t)(b * 4096 + n0)) * 2048;
  const char* Wbase = (const char*)PWh;

  auto stageload = [&](int s) {
    #pragma unroll
    for (int p = 0; p < 2; ++p) {
      int i = t + p * 256, row = i >> 3, slot = i & 7;
      areg[p] = *(const uint4*)(Fbase + (size_t)row * 2048 + s * 128 + slot * 16);
    }
    #pragma unroll
    for (int p = 0; p < 4; ++p) {
      int i = t + p * 256, row = i >> 3, slot = i & 7;
      wreg[p] = *(const uint4*)(Wbase + (size_t)row * 2048 + s * 128 + slot * 16);
    }
  };
  auto stagewrite = [&](int buf) {
    char* base = smem + buf * 24576;
    #pragma unroll
    for (int p = 0; p < 2; ++p) {
      int i = t + p * 256, row = i >> 3, slot = i & 7;
      *(uint4*)(base + row * 128 + ((slot * 16) ^ ((row & 7) << 4))) = areg[p];
    }
    #pragma unroll
    for (int p = 0; p < 4; ++p) {
      int i = t + p * 256, row = i >> 3, slot = i & 7;
      *(uint4*)(base + 8192 + row * 128 + ((slot * 16) ^ ((row & 7) << 4))) = wreg[p];
    }
  };

  const f32x4 zero4 = {0.f, 0.f, 0.f, 0.f};
  f32x4 acc[2][4];
  #pragma unroll
  for (int i2 = 0; i2 < 2; ++i2)
    #pragma unroll
    for (int j2 = 0; j2 < 4; ++j2) acc[i2][j2] = zero4;

  stageload(0); stagewrite(0);
  for (int s = 0; s < 16; ++s) {
    __syncthreads();
    if (s < 15) stageload(s + 1);
    const char* base = smem + (s & 1) * 24576;
    #pragma unroll
    for (int kk = 0; kk < 2; ++kk) {
      const int cb = kk * 64 + hi * 16;
      h8 af[2], bf[4];
      #pragma unroll
      for (int i2 = 0; i2 < 2; ++i2) {
        int row = nb + i2 * 16 + lo;
        af[i2] = *(const h8*)(base + row * 128 + (cb ^ ((row & 7) << 4)));
      }
      #pragma unroll
      for (int j2 = 0; j2 < 4; ++j2) {
        int row = ob + j2 * 16 + lo;
        bf[j2] = *(const h8*)(base + 8192 + row * 128 + (cb ^ ((row & 7) << 4)));
      }
      #pragma unroll
      for (int i2 = 0; i2 < 2; ++i2)
        #pragma unroll
        for (int j2 = 0; j2 < 4; ++j2)
          acc[i2][j2] = __builtin_amdgcn_mfma_f32_16x16x32_f16(af[i2], bf[j2], acc[i2][j2], 0, 0, 0);
    }
    if (s < 15) stagewrite((s + 1) & 1);
  }

  #pragma unroll
  for (int i2 = 0; i2 < 2; ++i2)
    #pragma unroll
    for (int j2 = 0; j2 < 4; ++j2)
      #pragma unroll
      for (int r = 0; r < 4; ++r) {
        int n = n0 + nb + i2 * 16 + hi * 4 + r;
        int o = ob + j2 * 16 + lo;
        *(_Float16*)(ftbase + ((size_t)(b * 4096 + n)) * 2048 + o * 2) = (_Float16)acc[i2][j2][r];
      }
}

// ---------------- kernel 3: GEMM2  qkvt[b][n][o3] = F2D[b][n][:] . Wh[o3][:] + bc ----------------
// M=128(n-tile) x N=128(o-group) x K=128 single shot, gll-staged.
__global__ void k_gemm2(const char* __restrict__ ftbase, const _Float16* __restrict__ Wh,
                        const float* __restrict__ bc, _Float16* __restrict__ qkvt)
{
  extern __shared__ char smem[];                     // A 32K + B 32K
  const int t = threadIdx.x, lane = t & 63, w = t >> 6;
  const int lo = lane & 15, hi = lane >> 4;
  const int bx = blockIdx.x, n0 = blockIdx.y * 128, b = blockIdx.z;
  const int wr = w >> 1, wc = w & 1;
  const int nb = wr * 64, ob = wc * 64;

  // stage A (F2D rows, 256B each inside 2048B FT rows) and B (Wh rows, 256B)
  #pragma unroll
  for (int q = 0; q < 8; ++q) {
    int c = w * 8 + q;
    int row = c * 4 + (lane >> 4);
    int col = ((lane & 15) * 16) ^ ((row & 7) << 4);
    gll16(ftbase + ((size_t)(b * 4096 + n0 + row)) * 2048 + col, smem + c * 1024);
    gll16((const char*)Wh + (size_t)(bx * 128 + row) * 256 + col, smem + 32768 + c * 1024);
  }
  __syncthreads();

  const f32x4 zero4 = {0.f, 0.f, 0.f, 0.f};
  f32x4 acc[4][4];
  #pragma unroll
  for (int i2 = 0; i2 < 4; ++i2)
    #pragma unroll
    for (int j2 = 0; j2 < 4; ++j2) acc[i2][j2] = zero4;

  #pragma unroll
  for (int kk = 0; kk < 4; ++kk) {
    const int cb = kk * 64 + hi * 16;
    h8 af[4], bf[4];
    #pragma unroll
    for (int i2 = 0; i2 < 4; ++i2) {
      int row = nb + i2 * 16 + lo;
      af[i2] = *(const h8*)(smem + row * 256 + (cb ^ ((row & 7) << 4)));
    }
    #pragma unroll
    for (int j2 = 0; j2 < 4; ++j2) {
      int row = ob + j2 * 16 + lo;
      bf[j2] = *(const h8*)(smem + 32768 + row * 256 + (cb ^ ((row & 7) << 4)));
    }
    #pragma unroll
    for (int i2 = 0; i2 < 4; ++i2)
      #pragma unroll
      for (int j2 = 0; j2 < 4; ++j2)
        acc[i2][j2] = __builtin_amdgcn_mfma_f32_16x16x32_f16(af[i2], bf[j2], acc[i2][j2], 0, 0, 0);
  }

  #pragma unroll
  for (int j2 = 0; j2 < 4; ++j2) {
    int o = bx * 128 + ob + j2 * 16 + lo;
    float bias = bc[o];
    #pragma unroll
    for (int i2 = 0; i2 < 4; ++i2)
      #pragma unroll
      for (int r = 0; r < 4; ++r) {
        int n = n0 + nb + i2 * 16 + hi * 4 + r;
        qkvt[((size_t)(b * 4096 + n)) * 384 + o] = (_Float16)(acc[i2][j2][r] + bias);
      }
  }
}

// ---------------- kernel 4: v slice of qkvt (n-major) -> v_t[b][d][m] (d-major) ----------------
__global__ void k_vtrans(const _Float16* __restrict__ qkvt, _Float16* __restrict__ vt)
{
  __shared__ char tl[64 * 256];
  const int mt = blockIdx.x, b = blockIdx.y, t = threadIdx.x;
  const int m0 = mt * 64;
  #pragma unroll
  for (int p = 0; p < 4; ++p) {
    int i = t + p * 256, m = i >> 4, slot = i & 15;
    uint4 g = *(const uint4*)((const char*)qkvt + ((size_t)(b * 4096 + m0 + m)) * 768 + 512 + slot * 16);
    *(uint4*)(tl + m * 256 + ((slot * 16) ^ ((m & 7) << 4))) = g;
  }
  __syncthreads();
  #pragma unroll
  for (int p = 0; p < 8; ++p) {
    int i = t + p * 256, d = i >> 4, ms = i & 15;
    h4 o;
    #pragma unroll
    for (int j = 0; j < 4; ++j) {
      int m = ms * 4 + j;
      o[j] = *(const _Float16*)(tl + m * 256 + ((2 * d) ^ ((m & 7) << 4)));
    }
    *(h4*)((char*)vt + ((size_t)(b * 128 + d)) * 8192 + (m0 + ms * 4) * 2) = o;
  }
}

// ---------------- kernel 5: split-KV flash attention, swapped-QK, in-register softmax ----------------
// grid 1024 = 4p x 4b x 64qt; 64 q/block, 4 waves x 16 q. KVBLK=32, LDS double-buffered via
// global_load_lds (pre-swizzled source, linear dest), one barrier per iter.
#define ATT_LDS 32768
__global__ __launch_bounds__(256, 4) void k_attn_part(const _Float16* __restrict__ qkvt,
                                                      const _Float16* __restrict__ vt,
                                                      float* __restrict__ opart,
                                                      float* __restrict__ mlm,
                                                      float* __restrict__ mll)
{
  extern __shared__ char smem[];                     // buf*16K: K[32][256B] ; +8K: V[128][64B]
  const int t = threadIdx.x, lane = t & 63, w = t >> 6;
  const int lo = lane & 15, hi = lane >> 4;
  const int id = blockIdx.x;
  const int vid = (id & 7) * 128 + (id >> 3);        // XCD-pinned: XCD x gets bp {2x,2x+1}
  const int qt = vid & 63, bp = vid >> 6;
  const int b = bp >> 2, p = bp & 3;
  const int n0 = qt * 64;
  const char* qbase = (const char*)qkvt + (size_t)b * 4096 * 768;
  const char* vbase = (const char*)vt + (size_t)b * 128 * 8192;

  // Q B-fragments from global (one-time)
  h8 bq[4];
  {
    const char* qr = qbase + (size_t)(n0 + w * 16 + lo) * 768;
    #pragma unroll
    for (int dk = 0; dk < 4; ++dk) bq[dk] = *(const h8*)(qr + dk * 64 + hi * 16);
  }

  // per-lane staging offsets (source pre-swizzled; LDS dest linear = base + lane*16)
  int koff[2], voff[2];
  #pragma unroll
  for (int q = 0; q < 2; ++q) {
    int c = w * 2 + q;
    int krow = c * 4 + (lane >> 4);                  // key row 0..31
    koff[q] = krow * 768 + 256 + (((lane & 15) * 16) ^ ((krow & 7) << 4));
    int d = c * 16 + (lane >> 2);                    // d row 0..127
    voff[q] = d * 64 + (((lane & 3) * 16) ^ (((lane >> 3) & 3) << 4));
  }
  const int kdst[2] = { (w * 2 + 0) * 1024, (w * 2 + 1) * 1024 };

  auto stage = [&](int m0, int buf) {
    char* kb = smem + buf * 16384;
    char* vb = kb + 8192;
    #pragma unroll
    for (int q = 0; q < 2; ++q) {
      gll16(qbase + (size_t)m0 * 768 + koff[q], kb + kdst[q]);
      gll16(vbase + (size_t)m0 * 2 + ((voff[q] >> 6) << 13) + (voff[q] & 63), vb + kdst[q]);
    }
  };

  const f32x4 zero4 = {0.f, 0.f, 0.f, 0.f};
  float m_run = -1e30f, l_run = 0.f;
  f32x4 oacc[8];
  #pragma unroll
  for (int dt = 0; dt < 8; ++dt) oacc[dt] = zero4;

  const int slA = (hi & 1) * 32 + lo, slB = slA + 16;
  const bool up = (hi & 2) != 0;

  stage(p * 1024, 0);
  __syncthreads();

  for (int it = 0; it < 32; ++it) {
    const int buf = it & 1;
    if (it < 31) stage(p * 1024 + (it + 1) * 32, buf ^ 1);

    const char* kb = smem + buf * 16384;
    const char* vb = kb + 8192;

    // ---- S^T = K Q  (rows=keys, cols=queries; lane holds 8 keys of query lo) ----
    f32x4 s[2];
    s[0] = zero4; s[1] = zero4;
    __builtin_amdgcn_s_setprio(1);
    #pragma unroll
    for (int mt = 0; mt < 2; ++mt) {
      #pragma unroll
      for (int dk = 0; dk < 4; ++dk) {
        int row = mt * 16 + lo;
        h8 ak = *(const h8*)(kb + row * 256 + ((dk * 64 + hi * 16) ^ ((row & 7) << 4)));
        s[mt] = __builtin_amdgcn_mfma_f32_16x16x32_f16(ak, bq[dk], s[mt], 0, 0, 0);
      }
    }
    __builtin_amdgcn_s_setprio(0);

    // ---- in-register online softmax (per-lane: query lo) ----
    float mx = fmaxf(fmaxf(fmaxf(s[0][0], s[0][1]), fmaxf(s[0][2], s[0][3])),
                     fmaxf(fmaxf(s[1][0], s[1][1]), fmaxf(s[1][2], s[1][3])));
    mx = fmaxf(mx, __shfl_xor(mx, 16));
    mx = fmaxf(mx, __shfl_xor(mx, 32));
    float mnew = fmaxf(m_run, mx);
    float sc = __expf(m_run - mnew);
    m_run = mnew;
    float rs = 0.f;
    uint32_t pk[2][2];
    #pragma unroll
    for (int mt = 0; mt < 2; ++mt) {
      float p0 = __expf(s[mt][0] - mnew), p1 = __expf(s[mt][1] - mnew);
      float p2 = __expf(s[mt][2] - mnew), p3 = __expf(s[mt][3] - mnew);
      rs += (p0 + p1) + (p2 + p3);
      pk[mt][0] = __builtin_bit_cast(uint32_t, __builtin_amdgcn_cvt_pkrtz(p0, p1));
      pk[mt][1] = __builtin_bit_cast(uint32_t, __builtin_amdgcn_cvt_pkrtz(p2, p3));
    }
    rs += __shfl_xor(rs, 16);
    rs += __shfl_xor(rs, 32);
    l_run = l_run * sc + rs;

    // rescale O (col = query lo everywhere)
    #pragma unroll
    for (int dt = 0; dt < 8; ++dt) oacc[dt] *= sc;

    // ---- build P^T B-fragment via lane exchange (keys hi*8..hi*8+7 for query lo) ----
    uint32_t w0a = __shfl(pk[0][0], slA), w0b = __shfl(pk[1][0], slA);
    uint32_t w1a = __shfl(pk[0][1], slA), w1b = __shfl(pk[1][1], slA);
    uint32_t w2a = __shfl(pk[0][0], slB), w2b = __shfl(pk[1][0], slB);
    uint32_t w3a = __shfl(pk[0][1], slB), w3b = __shfl(pk[1][1], slB);
    u32x4 bw = { up ? w0b : w0a, up ? w1b : w1a, up ? w2b : w2a, up ? w3b : w3a };
    h8 bpf = __builtin_bit_cast(h8, bw);

    // ---- O^T += V^T P^T ----
    __builtin_amdgcn_s_setprio(1);
    #pragma unroll
    for (int dt = 0; dt < 8; ++dt) {
      int d = dt * 16 + lo;
      h8 av = *(const h8*)(vb + d * 64 + ((hi * 16) ^ (((lo >> 1) & 3) << 4)));
      oacc[dt] = __builtin_amdgcn_mfma_f32_16x16x32_f16(av, bpf, oacc[dt], 0, 0, 0);
    }
    __builtin_amdgcn_s_setprio(0);

    if (it < 31) __syncthreads();                    // drains gll (vmcnt) + syncs buffers
  }

  // ---- store unnormalized partial O^T [p][b][d][n] + per-query (m,l) ----
  float* op = opart + ((size_t)((p * 4 + b) * 128)) * 4096;
  const int ncol = n0 + w * 16 + lo;
  #pragma unroll
  for (int dt = 0; dt < 8; ++dt)
    #pragma unroll
    for (int r = 0; r < 4; ++r) {
      int d = dt * 16 + hi * 4 + r;
      op[(size_t)d * 4096 + ncol] = oacc[dt][r];
    }
  if (hi == 0) {
    size_t mlbase = (size_t)(p * 4 + b) * 4096 + ncol;
    mlm[mlbase] = m_run;
    mll[mlbase] = l_run;
  }
}

// ---------------- kernel 6: combine 4 KV-partials ----------------
__global__ void k_reduce(const float* __restrict__ opart, const float* __restrict__ mlm,
                         const float* __restrict__ mll, float* __restrict__ out)
{
  int idx = blockIdx.x * 256 + threadIdx.x;          // 4b*128d*1024(n/4)
  int n4 = idx & 1023, d = (idx >> 10) & 127, b = idx >> 17;
  int n0 = n4 * 4;
  f32x4 m[4], lv[4];
  #pragma unroll
  for (int p = 0; p < 4; ++p) {
    size_t mb = (size_t)(p * 4 + b) * 4096 + n0;
    m[p]  = *(const f32x4*)(mlm + mb);
    lv[p] = *(const f32x4*)(mll + mb);
  }
  f32x4 M = m[0];
  #pragma unroll
  for (int p = 1; p < 4; ++p)
    #pragma unroll
    for (int j = 0; j < 4; ++j) M[j] = fmaxf(M[j], m[p][j]);
  f32x4 denom = {0.f, 0.f, 0.f, 0.f}, num = {0.f, 0.f, 0.f, 0.f};
  #pragma unroll
  for (int p = 0; p < 4; ++p) {
    f32x4 o = *(const f32x4*)(opart + ((size_t)((p * 4 + b) * 128 + d)) * 4096 + n0);
    #pragma unroll
    for (int j = 0; j < 4; ++j) {
      float e = __expf(m[p][j] - M[j]);
      denom[j] += lv[p][j] * e;
      num[j]   += o[j] * e;
    }
  }
  f32x4 r;
  #pragma unroll
  for (int j = 0; j < 4; ++j) r[j] = num[j] / denom[j];
  *(f32x4*)(out + ((size_t)(b * 128 + d)) * 4096 + n0) = r;
}

extern "C" void kernel_launch(void* const* d_in, const int* in_sizes, int n_in,
                              void* d_out, int out_size, void* d_ws, size_t ws_size,
                              hipStream_t stream)
{
  const float* feats = (const float*)d_in[0];
  const float* pw = (const float*)d_in[1];
  const float* pb = (const float*)d_in[2];
  const float* w1 = (const float*)d_in[3];
  const float* b1 = (const float*)d_in[4];
  const float* w2 = (const float*)d_in[5];
  const float* b2 = (const float*)d_in[6];
  const float* w3 = (const float*)d_in[7];
  const float* b3 = (const float*)d_in[8];
  char* ws = (char*)d_ws;
  _Float16* PWh = (_Float16*)(ws + WS_PWH);
  _Float16* Wh = (_Float16*)(ws + WS_WH);
  float* bc = (float*)(ws + WS_BC);
  char* ftbase = ws + WS_FT;
  _Float16* FT = (_Float16*)(ws + WS_FT);
  _Float16* qkvt = (_Float16*)(ws + WS_QKVT);
  _Float16* vt = (_Float16*)(ws + WS_VT);
  float* opart = (float*)(ws + WS_OP);
  float* mlm = (float*)(ws + WS_MLM);
  float* mll = (float*)(ws + WS_MLL);
  float* out = (float*)d_out;

  hipLaunchKernelGGL(k_cvt, dim3(704), dim3(256), 0, stream,
                     pw, pb, w1, b1, w2, b2, w3, b3, PWh, Wh, bc);
  hipLaunchKernelGGL(k_featT, dim3(16, 64, 4), dim3(256), 0, stream, feats, FT);
  hipLaunchKernelGGL(k_gemm1, dim3(64, 4), dim3(256), 49152, stream, ftbase, PWh);
  hipLaunchKernelGGL(k_gemm2, dim3(3, 32, 4), dim3(256), 65536, stream, ftbase, Wh, bc, qkvt);
  hipLaunchKernelGGL(k_vtrans, dim3(64, 4), dim3(256), 0, stream, qkvt, vt);
  hipLaunchKernelGGL(k_attn_part, dim3(1024), dim3(256), ATT_LDS, stream, qkvt, vt, opart, mlm, mll);
  hipLaunchKernelGGL(k_reduce, dim3(2048), dim3(256), 0, stream, opart, mlm, mll, out);
}

// Round 4
// 154.928 us; speedup vs baseline: 2.6513x; 1.0070x over previous
//
#include <hip/hip_runtime.h>
#include <stdint.h>

typedef _Float16 h8 __attribute__((ext_vector_type(8)));
typedef _Float16 h4 __attribute__((ext_vector_type(4)));
typedef float f32x4 __attribute__((ext_vector_type(4)));
typedef uint32_t u32x4 __attribute__((ext_vector_type(4)));

#if __has_builtin(__builtin_amdgcn_exp2f)
#define EXP2(x) __builtin_amdgcn_exp2f(x)
#else
#define EXP2(x) exp2f(x)
#endif

// workspace map (<= 51380224 bytes)
#define WS_PWH  0u          // _Float16 [128][1024]  (dead after gemm1; mlm overwrites)
#define WS_WH   262144u     // _Float16 [384][128]   (dead after gemm2; mll overwrites)
#define WS_BC   600064u     // float [384]           (dead after gemm2)
#define WS_FT   1048576u    // _Float16 [4][4096][1024] feats^T; F2D aliases first 256B of rows
#define WS_QKVT 34603008u   // _Float16 [4][4096][384] q|k|v, n-major
#define WS_VT   47185920u   // _Float16 [4][128][4096] v, d-major
#define WS_OP   WS_FT       // _Float16 [32 pb][128 d][4096 n] normalized partial O (33.5MB over FT)
#define WS_MLM  0u          // float [32][4096] running max (log2 domain)
#define WS_MLL  524288u     // float [32][4096] running sum

__device__ __forceinline__ void gll16(const void* g, void* l) {
  __builtin_amdgcn_global_load_lds((const __attribute__((address_space(1))) unsigned int*)g,
                                   (__attribute__((address_space(3))) unsigned int*)l, 16, 0, 0);
}

// ---------------- kernel 0: casts + combined bias bc = b + W*pb; q-weights scaled by log2(e) ----------------
__global__ void k_cvt(const float* __restrict__ pw, const float* __restrict__ pb,
                      const float* __restrict__ w1, const float* __restrict__ b1,
                      const float* __restrict__ w2, const float* __restrict__ b2,
                      const float* __restrict__ w3, const float* __restrict__ b3,
                      _Float16* __restrict__ PWh, _Float16* __restrict__ Wh,
                      float* __restrict__ bc)
{
  const float LOG2E = 1.4426950408889634f;
  int idx = blockIdx.x * 256 + threadIdx.x;
  if (idx < 131072) {
    PWh[idx] = (_Float16)pw[idx];
  } else {
    int j = idx - 131072;
    if (j < 49152) {
      int g = j >> 14, rem = j & 16383;
      const float* wg = (g == 0) ? w1 : (g == 1 ? w2 : w3);
      float v = wg[rem];
      if (g == 0) v *= LOG2E;                        // q in log2 domain
      Wh[j] = (_Float16)v;
    }
  }
  if (idx < 384) {
    int g = idx >> 7, o = idx & 127;
    const float* wg = (g == 0) ? w1 : (g == 1 ? w2 : w3);
    const float* bg = (g == 0) ? b1 : (g == 1 ? b2 : b3);
    float s = bg[o];
    for (int c = 0; c < 128; ++c) s += wg[o * 128 + c] * pb[c];
    if (g == 0) s *= LOG2E;
    bc[idx] = s;
  }
}

// ---------------- kernel 1: feats (b,1024,4096) f32 -> feats^T (b,4096,1024) fp16 ----------------
__global__ void k_featT(const float* __restrict__ feats, _Float16* __restrict__ FT)
{
  __shared__ float tile[64][65];
  const int ck0 = blockIdx.x * 64, n0 = blockIdx.y * 64, b = blockIdx.z;
  const int t = threadIdx.x;
  const float* src = feats + ((size_t)(b * 1024 + ck0)) * 4096 + n0;
  #pragma unroll
  for (int p = 0; p < 4; ++p) {
    int i = t + p * 256, row = i >> 4, slot = i & 15;
    float4 g = *(const float4*)(src + (size_t)row * 4096 + slot * 4);
    tile[row][slot * 4 + 0] = g.x; tile[row][slot * 4 + 1] = g.y;
    tile[row][slot * 4 + 2] = g.z; tile[row][slot * 4 + 3] = g.w;
  }
  __syncthreads();
  _Float16* dst = FT + ((size_t)(b * 4096 + n0)) * 1024 + ck0;
  #pragma unroll
  for (int p = 0; p < 4; ++p) {
    int i = t + p * 256, n = i >> 4, cs = i & 15;
    h4 o;
    #pragma unroll
    for (int j = 0; j < 4; ++j) o[j] = (_Float16)tile[cs * 4 + j][n];
    *(h4*)(dst + (size_t)n * 1024 + cs * 4) = o;
  }
}

// ---------------- kernel 2: GEMM1  F2D[b][n][128] = FT[b][n][:] . PWh[o][:] ----------------
__global__ __launch_bounds__(256) void k_gemm1(char* __restrict__ ftbase,
                                               const _Float16* __restrict__ PWh)
{
  extern __shared__ char smem[];                     // 2 bufs x (A 8K + B 16K) = 48K
  const int t = threadIdx.x, lane = t & 63, w = t >> 6;
  const int lo = lane & 15, hi = lane >> 4;
  const int n0 = blockIdx.x * 64, b = blockIdx.y;
  const int wr = w >> 1, wc = w & 1;
  const int nb = wr * 32, ob = wc * 64;

  uint4 areg[2], wreg[4];
  const char* Fbase = ftbase + ((size_t)(b * 4096 + n0)) * 2048;
  const char* Wbase = (const char*)PWh;

  auto stageload = [&](int s) {
    #pragma unroll
    for (int p = 0; p < 2; ++p) {
      int i = t + p * 256, row = i >> 3, slot = i & 7;
      areg[p] = *(const uint4*)(Fbase + (size_t)row * 2048 + s * 128 + slot * 16);
    }
    #pragma unroll
    for (int p = 0; p < 4; ++p) {
      int i = t + p * 256, row = i >> 3, slot = i & 7;
      wreg[p] = *(const uint4*)(Wbase + (size_t)row * 2048 + s * 128 + slot * 16);
    }
  };
  auto stagewrite = [&](int buf) {
    char* base = smem + buf * 24576;
    #pragma unroll
    for (int p = 0; p < 2; ++p) {
      int i = t + p * 256, row = i >> 3, slot = i & 7;
      *(uint4*)(base + row * 128 + ((slot * 16) ^ ((row & 7) << 4))) = areg[p];
    }
    #pragma unroll
    for (int p = 0; p < 4; ++p) {
      int i = t + p * 256, row = i >> 3, slot = i & 7;
      *(uint4*)(base + 8192 + row * 128 + ((slot * 16) ^ ((row & 7) << 4))) = wreg[p];
    }
  };

  const f32x4 zero4 = {0.f, 0.f, 0.f, 0.f};
  f32x4 acc[2][4];
  #pragma unroll
  for (int i2 = 0; i2 < 2; ++i2)
    #pragma unroll
    for (int j2 = 0; j2 < 4; ++j2) acc[i2][j2] = zero4;

  stageload(0); stagewrite(0);
  for (int s = 0; s < 16; ++s) {
    __syncthreads();
    if (s < 15) stageload(s + 1);
    const char* base = smem + (s & 1) * 24576;
    #pragma unroll
    for (int kk = 0; kk < 2; ++kk) {
      const int cb = kk * 64 + hi * 16;
      h8 af[2], bf[4];
      #pragma unroll
      for (int i2 = 0; i2 < 2; ++i2) {
        int row = nb + i2 * 16 + lo;
        af[i2] = *(const h8*)(base + row * 128 + (cb ^ ((row & 7) << 4)));
      }
      #pragma unroll
      for (int j2 = 0; j2 < 4; ++j2) {
        int row = ob + j2 * 16 + lo;
        bf[j2] = *(const h8*)(base + 8192 + row * 128 + (cb ^ ((row & 7) << 4)));
      }
      #pragma unroll
      for (int i2 = 0; i2 < 2; ++i2)
        #pragma unroll
        for (int j2 = 0; j2 < 4; ++j2)
          acc[i2][j2] = __builtin_amdgcn_mfma_f32_16x16x32_f16(af[i2], bf[j2], acc[i2][j2], 0, 0, 0);
    }
    if (s < 15) stagewrite((s + 1) & 1);
  }

  #pragma unroll
  for (int i2 = 0; i2 < 2; ++i2)
    #pragma unroll
    for (int j2 = 0; j2 < 4; ++j2)
      #pragma unroll
      for (int r = 0; r < 4; ++r) {
        int n = n0 + nb + i2 * 16 + hi * 4 + r;
        int o = ob + j2 * 16 + lo;
        *(_Float16*)(ftbase + ((size_t)(b * 4096 + n)) * 2048 + o * 2) = (_Float16)acc[i2][j2][r];
      }
}

// ---------------- kernel 3: GEMM2  qkvt[b][n][o3] = F2D[b][n][:] . Wh[o3][:] + bc ----------------
__global__ void k_gemm2(const char* __restrict__ ftbase, const _Float16* __restrict__ Wh,
                        const float* __restrict__ bc, _Float16* __restrict__ qkvt)
{
  extern __shared__ char smem[];                     // A 32K + B 32K
  const int t = threadIdx.x, lane = t & 63, w = t >> 6;
  const int lo = lane & 15, hi = lane >> 4;
  const int bx = blockIdx.x, n0 = blockIdx.y * 128, b = blockIdx.z;
  const int wr = w >> 1, wc = w & 1;
  const int nb = wr * 64, ob = wc * 64;

  #pragma unroll
  for (int q = 0; q < 8; ++q) {
    int c = w * 8 + q;
    int row = c * 4 + (lane >> 4);
    int col = ((lane & 15) * 16) ^ ((row & 7) << 4);
    gll16(ftbase + ((size_t)(b * 4096 + n0 + row)) * 2048 + col, smem + c * 1024);
    gll16((const char*)Wh + (size_t)(bx * 128 + row) * 256 + col, smem + 32768 + c * 1024);
  }
  __syncthreads();

  const f32x4 zero4 = {0.f, 0.f, 0.f, 0.f};
  f32x4 acc[4][4];
  #pragma unroll
  for (int i2 = 0; i2 < 4; ++i2)
    #pragma unroll
    for (int j2 = 0; j2 < 4; ++j2) acc[i2][j2] = zero4;

  #pragma unroll
  for (int kk = 0; kk < 4; ++kk) {
    const int cb = kk * 64 + hi * 16;
    h8 af[4], bf[4];
    #pragma unroll
    for (int i2 = 0; i2 < 4; ++i2) {
      int row = nb + i2 * 16 + lo;
      af[i2] = *(const h8*)(smem + row * 256 + (cb ^ ((row & 7) << 4)));
    }
    #pragma unroll
    for (int j2 = 0; j2 < 4; ++j2) {
      int row = ob + j2 * 16 + lo;
      bf[j2] = *(const h8*)(smem + 32768 + row * 256 + (cb ^ ((row & 7) << 4)));
    }
    #pragma unroll
    for (int i2 = 0; i2 < 4; ++i2)
      #pragma unroll
      for (int j2 = 0; j2 < 4; ++j2)
        acc[i2][j2] = __builtin_amdgcn_mfma_f32_16x16x32_f16(af[i2], bf[j2], acc[i2][j2], 0, 0, 0);
  }

  #pragma unroll
  for (int j2 = 0; j2 < 4; ++j2) {
    int o = bx * 128 + ob + j2 * 16 + lo;
    float bias = bc[o];
    #pragma unroll
    for (int i2 = 0; i2 < 4; ++i2)
      #pragma unroll
      for (int r = 0; r < 4; ++r) {
        int n = n0 + nb + i2 * 16 + hi * 4 + r;
        qkvt[((size_t)(b * 4096 + n)) * 384 + o] = (_Float16)(acc[i2][j2][r] + bias);
      }
  }
}

// ---------------- kernel 4: v slice of qkvt (n-major) -> v_t[b][d][m] (d-major) ----------------
__global__ void k_vtrans(const _Float16* __restrict__ qkvt, _Float16* __restrict__ vt)
{
  __shared__ char tl[64 * 256];
  const int mt = blockIdx.x, b = blockIdx.y, t = threadIdx.x;
  const int m0 = mt * 64;
  #pragma unroll
  for (int p = 0; p < 4; ++p) {
    int i = t + p * 256, m = i >> 4, slot = i & 15;
    uint4 g = *(const uint4*)((const char*)qkvt + ((size_t)(b * 4096 + m0 + m)) * 768 + 512 + slot * 16);
    *(uint4*)(tl + m * 256 + ((slot * 16) ^ ((m & 7) << 4))) = g;
  }
  __syncthreads();
  #pragma unroll
  for (int p = 0; p < 8; ++p) {
    int i = t + p * 256, d = i >> 4, ms = i & 15;
    h4 o;
    #pragma unroll
    for (int j = 0; j < 4; ++j) {
      int m = ms * 4 + j;
      o[j] = *(const _Float16*)(tl + m * 256 + ((2 * d) ^ ((m & 7) << 4)));
    }
    *(h4*)((char*)vt + ((size_t)(b * 128 + d)) * 8192 + (m0 + ms * 4) * 2) = o;
  }
}

// ---------------- kernel 5: split-KV(x8) flash attention, log2-domain, defer-max ----------------
// grid 2048 = 8p x 4b x 64qt; 64 q/block, 4 waves x 16 q. KVBLK=32, dbuf gll staging.
// Writes NORMALIZED partial O^T fp16 [pb][d][n] + per-query (m, l) f32.
#define ATT_LDS 32768
__global__ __launch_bounds__(256, 5) void k_attn_part(const _Float16* __restrict__ qkvt,
                                                      const _Float16* __restrict__ vt,
                                                      _Float16* __restrict__ opart,
                                                      float* __restrict__ mlm,
                                                      float* __restrict__ mll)
{
  extern __shared__ char smem[];                     // buf*16K: K[32][256B] ; +8K: V[128][64B]
  const int t = threadIdx.x, lane = t & 63, w = t >> 6;
  const int lo = lane & 15, hi = lane >> 4;
  const int id = blockIdx.x;
  const int vid = (id & 7) * 256 + (id >> 3);        // XCD x gets bp in {4x..4x+3}: one batch, 4 parts
  const int qt = vid & 63, bp = vid >> 6;
  const int b = bp >> 3, p = bp & 7;
  const int n0 = qt * 64;
  const char* qbase = (const char*)qkvt + (size_t)b * 4096 * 768;
  const char* vbase = (const char*)vt + (size_t)b * 128 * 8192;

  // Q B-fragments from global (one-time; already log2e-scaled upstream)
  h8 bq[4];
  {
    const char* qr = qbase + (size_t)(n0 + w * 16 + lo) * 768;
    #pragma unroll
    for (int dk = 0; dk < 4; ++dk) bq[dk] = *(const h8*)(qr + dk * 64 + hi * 16);
  }

  int koff[2], voff[2];
  #pragma unroll
  for (int q = 0; q < 2; ++q) {
    int c = w * 2 + q;
    int krow = c * 4 + (lane >> 4);
    koff[q] = krow * 768 + 256 + (((lane & 15) * 16) ^ ((krow & 7) << 4));
    int d = c * 16 + (lane >> 2);
    voff[q] = d * 64 + (((lane & 3) * 16) ^ (((lane >> 3) & 3) << 4));
  }
  const int kdst[2] = { (w * 2 + 0) * 1024, (w * 2 + 1) * 1024 };

  auto stage = [&](int m0, int buf) {
    char* kb = smem + buf * 16384;
    char* vb = kb + 8192;
    #pragma unroll
    for (int q = 0; q < 2; ++q) {
      gll16(qbase + (size_t)m0 * 768 + koff[q], kb + kdst[q]);
      gll16(vbase + (size_t)m0 * 2 + ((voff[q] >> 6) << 13) + (voff[q] & 63), vb + kdst[q]);
    }
  };

  const f32x4 zero4 = {0.f, 0.f, 0.f, 0.f};
  float m_run = -1e30f, l_run = 0.f;                 // l_run: per-lane partial (own 8 keys)
  f32x4 oacc[8];
  #pragma unroll
  for (int dt = 0; dt < 8; ++dt) oacc[dt] = zero4;

  const int slA = (hi & 1) * 32 + lo, slB = slA + 16;
  const bool up = (hi & 2) != 0;

  stage(p * 512, 0);
  __syncthreads();

  for (int it = 0; it < 16; ++it) {
    const int buf = it & 1;
    if (it < 15) stage(p * 512 + (it + 1) * 32, buf ^ 1);

    const char* kb = smem + buf * 16384;
    const char* vb = kb + 8192;

    // ---- S^T = K Q (log2 domain) ----
    f32x4 s[2];
    s[0] = zero4; s[1] = zero4;
    __builtin_amdgcn_s_setprio(1);
    #pragma unroll
    for (int mt = 0; mt < 2; ++mt) {
      #pragma unroll
      for (int dk = 0; dk < 4; ++dk) {
        int row = mt * 16 + lo;
        h8 ak = *(const h8*)(kb + row * 256 + ((dk * 64 + hi * 16) ^ ((row & 7) << 4)));
        s[mt] = __builtin_amdgcn_mfma_f32_16x16x32_f16(ak, bq[dk], s[mt], 0, 0, 0);
      }
    }
    __builtin_amdgcn_s_setprio(0);

    // ---- online softmax, defer-max THR=8 (p <= 2^8) ----
    float mx = fmaxf(fmaxf(fmaxf(s[0][0], s[0][1]), fmaxf(s[0][2], s[0][3])),
                     fmaxf(fmaxf(s[1][0], s[1][1]), fmaxf(s[1][2], s[1][3])));
    mx = fmaxf(mx, __shfl_xor(mx, 16));
    mx = fmaxf(mx, __shfl_xor(mx, 32));
    if (mx > m_run + 8.f) {                          // rare after first iter
      float scn = EXP2(m_run - mx);
      m_run = mx;
      l_run *= scn;
      #pragma unroll
      for (int dt = 0; dt < 8; ++dt) oacc[dt] *= scn;
    }
    uint32_t pk[2][2];
    float rs = 0.f;
    #pragma unroll
    for (int mt = 0; mt < 2; ++mt) {
      float p0 = EXP2(s[mt][0] - m_run), p1 = EXP2(s[mt][1] - m_run);
      float p2 = EXP2(s[mt][2] - m_run), p3 = EXP2(s[mt][3] - m_run);
      rs += (p0 + p1) + (p2 + p3);
      pk[mt][0] = __builtin_bit_cast(uint32_t, __builtin_amdgcn_cvt_pkrtz(p0, p1));
      pk[mt][1] = __builtin_bit_cast(uint32_t, __builtin_amdgcn_cvt_pkrtz(p2, p3));
    }
    l_run += rs;                                     // per-lane partial; reduced at end

    // ---- build P^T B-fragment via lane exchange ----
    uint32_t w0a = __shfl(pk[0][0], slA), w0b = __shfl(pk[1][0], slA);
    uint32_t w1a = __shfl(pk[0][1], slA), w1b = __shfl(pk[1][1], slA);
    uint32_t w2a = __shfl(pk[0][0], slB), w2b = __shfl(pk[1][0], slB);
    uint32_t w3a = __shfl(pk[0][1], slB), w3b = __shfl(pk[1][1], slB);
    u32x4 bw = { up ? w0b : w0a, up ? w1b : w1a, up ? w2b : w2a, up ? w3b : w3a };
    h8 bpf = __builtin_bit_cast(h8, bw);

    // ---- O^T += V^T P^T ----
    __builtin_amdgcn_s_setprio(1);
    #pragma unroll
    for (int dt = 0; dt < 8; ++dt) {
      int d = dt * 16 + lo;
      h8 av = *(const h8*)(vb + d * 64 + ((hi * 16) ^ (((lo >> 1) & 3) << 4)));
      oacc[dt] = __builtin_amdgcn_mfma_f32_16x16x32_f16(av, bpf, oacc[dt], 0, 0, 0);
    }
    __builtin_amdgcn_s_setprio(0);

    if (it < 15) __syncthreads();
  }

  // ---- finalize: reduce l over hi-lanes, store normalized fp16 partial + (m,l) ----
  l_run += __shfl_xor(l_run, 16);
  l_run += __shfl_xor(l_run, 32);
  float invl = 1.0f / l_run;
  _Float16* oph = opart + ((size_t)(p * 4 + b) * 128) * 4096;
  const int ncol = n0 + w * 16 + lo;
  #pragma unroll
  for (int dt = 0; dt < 8; ++dt)
    #pragma unroll
    for (int r = 0; r < 4; ++r) {
      int d = dt * 16 + hi * 4 + r;
      oph[(size_t)d * 4096 + ncol] = (_Float16)(oacc[dt][r] * invl);
    }
  if (hi == 0) {
    size_t mlbase = (size_t)(p * 4 + b) * 4096 + ncol;
    mlm[mlbase] = m_run;
    mll[mlbase] = l_run;
  }
}

// ---------------- kernel 6: combine 8 normalized KV-partials ----------------
__global__ void k_reduce(const _Float16* __restrict__ opart, const float* __restrict__ mlm,
                         const float* __restrict__ mll, float* __restrict__ out)
{
  int idx = blockIdx.x * 256 + threadIdx.x;          // 4b*128d*1024(n/4)
  int n4 = idx & 1023, d = (idx >> 10) & 127, b = idx >> 17;
  int n0 = n4 * 4;
  f32x4 m[8], lv[8];
  #pragma unroll
  for (int p = 0; p < 8; ++p) {
    size_t mb = (size_t)(p * 4 + b) * 4096 + n0;
    m[p]  = *(const f32x4*)(mlm + mb);
    lv[p] = *(const f32x4*)(mll + mb);
  }
  f32x4 M = m[0];
  #pragma unroll
  for (int p = 1; p < 8; ++p)
    #pragma unroll
    for (int j = 0; j < 4; ++j) M[j] = fmaxf(M[j], m[p][j]);
  f32x4 denom = {0.f, 0.f, 0.f, 0.f}, num = {0.f, 0.f, 0.f, 0.f};
  #pragma unroll
  for (int p = 0; p < 8; ++p) {
    h4 o = *(const h4*)(opart + ((size_t)((p * 4 + b) * 128 + d)) * 4096 + n0);
    #pragma unroll
    for (int j = 0; j < 4; ++j) {
      float wgt = lv[p][j] * EXP2(m[p][j] - M[j]);   // log2-domain m
      denom[j] += wgt;
      num[j]   += (float)o[j] * wgt;
    }
  }
  f32x4 r;
  #pragma unroll
  for (int j = 0; j < 4; ++j) r[j] = num[j] / denom[j];
  *(f32x4*)(out + ((size_t)(b * 128 + d)) * 4096 + n0) = r;
}

extern "C" void kernel_launch(void* const* d_in, const int* in_sizes, int n_in,
                              void* d_out, int out_size, void* d_ws, size_t ws_size,
                              hipStream_t stream)
{
  const float* feats = (const float*)d_in[0];
  const float* pw = (const float*)d_in[1];
  const float* pb = (const float*)d_in[2];
  const float* w1 = (const float*)d_in[3];
  const float* b1 = (const float*)d_in[4];
  const float* w2 = (const float*)d_in[5];
  const float* b2 = (const float*)d_in[6];
  const float* w3 = (const float*)d_in[7];
  const float* b3 = (const float*)d_in[8];
  char* ws = (char*)d_ws;
  _Float16* PWh = (_Float16*)(ws + WS_PWH);
  _Float16* Wh = (_Float16*)(ws + WS_WH);
  float* bc = (float*)(ws + WS_BC);
  char* ftbase = ws + WS_FT;
  _Float16* FT = (_Float16*)(ws + WS_FT);
  _Float16* qkvt = (_Float16*)(ws + WS_QKVT);
  _Float16* vt = (_Float16*)(ws + WS_VT);
  _Float16* opart = (_Float16*)(ws + WS_OP);
  float* mlm = (float*)(ws + WS_MLM);
  float* mll = (float*)(ws + WS_MLL);
  float* out = (float*)d_out;

  hipLaunchKernelGGL(k_cvt, dim3(704), dim3(256), 0, stream,
                     pw, pb, w1, b1, w2, b2, w3, b3, PWh, Wh, bc);
  hipLaunchKernelGGL(k_featT, dim3(16, 64, 4), dim3(256), 0, stream, feats, FT);
  hipLaunchKernelGGL(k_gemm1, dim3(64, 4), dim3(256), 49152, stream, ftbase, PWh);
  hipLaunchKernelGGL(k_gemm2, dim3(3, 32, 4), dim3(256), 65536, stream, ftbase, Wh, bc, qkvt);
  hipLaunchKernelGGL(k_vtrans, dim3(64, 4), dim3(256), 0, stream, qkvt, vt);
  hipLaunchKernelGGL(k_attn_part, dim3(2048), dim3(256), ATT_LDS, stream, qkvt, vt, opart, mlm, mll);
  hipLaunchKernelGGL(k_reduce, dim3(2048), dim3(256), 0, stream, opart, mlm, mll, out);
}